// Round 1
// baseline (226.937 us; speedup 1.0000x reference)
//
#include <hip/hip_runtime.h>
#include <hip/hip_bf16.h>
#include <stdint.h>

typedef _Float16 f16x8_t __attribute__((ext_vector_type(8)));
typedef _Float16 f16x4_t __attribute__((ext_vector_type(4)));
typedef float    f32x4_t __attribute__((ext_vector_type(4)));

#define T_SEQ 2048
#define NH    16
#define HD    64
#define CDIM  1024
#define NTOK  4096          // B*T
#define SCALE_F 0.125f      // 1/sqrt(64)

// ---------- async global->LDS, 16B per lane ----------
__device__ __forceinline__ void async_ld16(void* lds, const void* g) {
    __builtin_amdgcn_global_load_lds(
        (const __attribute__((address_space(1))) uint32_t*)g,
        (__attribute__((address_space(3))) uint32_t*)lds, 16, 0, 0);
}

// ---------- fp32 -> fp16 convert (vector x4) ----------
__global__ __launch_bounds__(256) void cvt_f32_f16(const float* __restrict__ src,
                                                   _Float16* __restrict__ dst, int n4) {
    int i = blockIdx.x * blockDim.x + threadIdx.x;
    if (i < n4) {
        float4 v = ((const float4*)src)[i];
        f16x4_t h;
        h[0] = (_Float16)v.x; h[1] = (_Float16)v.y;
        h[2] = (_Float16)v.z; h[3] = (_Float16)v.w;
        ((f16x4_t*)dst)[i] = h;
    }
}

// ---------- mask nonzero flag ----------
__global__ __launch_bounds__(256) void mask_flag_k(const float* __restrict__ mask, int n4,
                                                   int* __restrict__ flag) {
    int i = blockIdx.x * blockDim.x + threadIdx.x;
    int stride = gridDim.x * blockDim.x;
    int any = 0;
    for (; i < n4; i += stride) {
        float4 v = ((const float4*)mask)[i];
        any |= (v.x != 0.f) | (v.y != 0.f) | (v.z != 0.f) | (v.w != 0.f);
    }
    if (any) atomicOr(flag, 1);
}

// ---------- GEMM: C[M,N] = A[M,K] * B[N,K]^T (+bias) ----------
// MODE 0: QKV projection, N=3072, scatter to Q,K (B,H,T,D) and V^T (B,H,D,T), fp16 out
// MODE 1: out projection, N=1024, fp32 out to d_out
template<int MODE>
__global__ __launch_bounds__(256)
void gemm_f16(const _Float16* __restrict__ Ag, const _Float16* __restrict__ Bg,
              const float* __restrict__ b0, const float* __restrict__ b1,
              const float* __restrict__ b2,
              _Float16* __restrict__ Qo, _Float16* __restrict__ Ko,
              _Float16* __restrict__ Vto, float* __restrict__ Fo)
{
    __shared__ _Float16 sA[128 * 32];
    __shared__ _Float16 sB[128 * 32];
    const int K = CDIM;
    const int tid  = threadIdx.x;
    const int lane = tid & 63, wv = tid >> 6;
    const int wr = wv >> 1, wc = wv & 1;
    const int rowA0 = blockIdx.x * 128;
    const int rowB0 = blockIdx.y * 128;
    const int srow = lane >> 2;          // staging row within 16-row wave chunk
    const int scol = (lane & 3) * 8;     // staging col (halves)
    const int fr = lane & 15, fg = lane >> 4;
    f32x4_t acc[4][4] = {};

    for (int k0 = 0; k0 < K; k0 += 32) {
#pragma unroll
        for (int i = 0; i < 2; ++i) {
            const int eoff = i * 2048 + wv * 512;       // halves, wave-uniform LDS base
            const int r = (eoff >> 5) + srow;           // tile row 0..127
            async_ld16(&sA[eoff], Ag + (size_t)(rowA0 + r) * K + k0 + scol);
            async_ld16(&sB[eoff], Bg + (size_t)(rowB0 + r) * K + k0 + scol);
        }
        __syncthreads();
        f16x8_t a[4], b[4];
#pragma unroll
        for (int mi = 0; mi < 4; ++mi)
            a[mi] = *(const f16x8_t*)&sA[(wr * 64 + mi * 16 + fr) * 32 + fg * 8];
#pragma unroll
        for (int ni = 0; ni < 4; ++ni)
            b[ni] = *(const f16x8_t*)&sB[(wc * 64 + ni * 16 + fr) * 32 + fg * 8];
#pragma unroll
        for (int mi = 0; mi < 4; ++mi)
#pragma unroll
            for (int ni = 0; ni < 4; ++ni)
                acc[mi][ni] = __builtin_amdgcn_mfma_f32_16x16x32_f16(a[mi], b[ni], acc[mi][ni], 0, 0, 0);
        __syncthreads();
    }

#pragma unroll
    for (int mi = 0; mi < 4; ++mi) {
#pragma unroll
        for (int ni = 0; ni < 4; ++ni) {
            const int col = rowB0 + wc * 64 + ni * 16 + fr;
#pragma unroll
            for (int r = 0; r < 4; ++r) {
                const int row = rowA0 + wr * 64 + mi * 16 + fg * 4 + r;
                float v = acc[mi][ni][r];
                if (MODE == 0) {
                    const int which = col >> 10, cc = col & 1023;
                    const float* bp = (which == 0) ? b0 : ((which == 1) ? b1 : b2);
                    v += bp[cc];
                    const int bb = row >> 11, t = row & (T_SEQ - 1);
                    const int h = cc >> 6, d = cc & 63;
                    const int bh = bb * NH + h;
                    if (which == 0)
                        Qo[((size_t)bh * T_SEQ + t) * HD + d] = (_Float16)(v * SCALE_F);
                    else if (which == 1)
                        Ko[((size_t)bh * T_SEQ + t) * HD + d] = (_Float16)v;
                    else
                        Vto[((size_t)bh * HD + d) * T_SEQ + t] = (_Float16)v;
                } else {
                    Fo[(size_t)row * CDIM + col] = v + b0[col];
                }
            }
        }
    }
}

// ---------- flash attention, fp16, online softmax ----------
// grid (T/128, B*H), 256 threads; each wave owns 32 q-rows; KV tile = 32
__global__ __launch_bounds__(256)
void attn_f16(const _Float16* __restrict__ Q, const _Float16* __restrict__ Kg,
              const _Float16* __restrict__ Vt, const float* __restrict__ mask,
              const int* __restrict__ mflag, _Float16* __restrict__ AO)
{
    __shared__ _Float16 Ps[4][32][40];   // per-wave P transpose buffer, 80B rows (conflict-free b128)
    const int tid = threadIdx.x;
    const int lane = tid & 63, wv = tid >> 6;
    const int fr = lane & 15, fg = lane >> 4;
    const int bh = blockIdx.y;
    const int b = bh >> 4, h = bh & (NH - 1);
    const int q0 = blockIdx.x * 128 + wv * 32;
    const _Float16* Qb = Q  + (size_t)bh * T_SEQ * HD;
    const _Float16* Kb = Kg + (size_t)bh * T_SEQ * HD;
    const _Float16* Vb = Vt + (size_t)bh * HD * T_SEQ;

    f16x8_t qf[2][2];
#pragma unroll
    for (int qi = 0; qi < 2; ++qi)
#pragma unroll
        for (int dc = 0; dc < 2; ++dc)
            qf[qi][dc] = *(const f16x8_t*)&Qb[(size_t)(q0 + qi * 16 + fr) * HD + dc * 32 + fg * 8];

    f32x4_t o[2][4] = {};
    float m_run[2][4], l_run[2][4];
#pragma unroll
    for (int qi = 0; qi < 2; ++qi)
#pragma unroll
        for (int r = 0; r < 4; ++r) { m_run[qi][r] = -1e30f; l_run[qi][r] = 0.f; }

    const int mf = mflag[0];

    for (int t = 0; t < T_SEQ / 32; ++t) {
        const int k0 = t * 32;
        f16x8_t kf[2][2];
#pragma unroll
        for (int ki = 0; ki < 2; ++ki)
#pragma unroll
            for (int dc = 0; dc < 2; ++dc)
                kf[ki][dc] = *(const f16x8_t*)&Kb[(size_t)(k0 + ki * 16 + fr) * HD + dc * 32 + fg * 8];
        f32x4_t s[2][2] = {};
#pragma unroll
        for (int qi = 0; qi < 2; ++qi)
#pragma unroll
            for (int ki = 0; ki < 2; ++ki)
#pragma unroll
                for (int dc = 0; dc < 2; ++dc)
                    s[qi][ki] = __builtin_amdgcn_mfma_f32_16x16x32_f16(qf[qi][dc], kf[ki][dc], s[qi][ki], 0, 0, 0);
        if (mf) {
#pragma unroll
            for (int qi = 0; qi < 2; ++qi)
#pragma unroll
                for (int ki = 0; ki < 2; ++ki)
#pragma unroll
                    for (int r = 0; r < 4; ++r)
                        s[qi][ki][r] += mask[(size_t)(q0 + qi * 16 + fg * 4 + r) * T_SEQ + k0 + ki * 16 + fr];
        }
        // online softmax (rows live across 16-lane groups: row = fg*4+r, col = fr)
#pragma unroll
        for (int qi = 0; qi < 2; ++qi) {
#pragma unroll
            for (int r = 0; r < 4; ++r) {
                float tmax = fmaxf(s[qi][0][r], s[qi][1][r]);
#pragma unroll
                for (int mm = 1; mm < 16; mm <<= 1)
                    tmax = fmaxf(tmax, __shfl_xor(tmax, mm, 64));
                const float mnew = fmaxf(m_run[qi][r], tmax);
                const float sc = __expf(m_run[qi][r] - mnew);
                m_run[qi][r] = mnew;
                const float p0 = __expf(s[qi][0][r] - mnew);
                const float p1 = __expf(s[qi][1][r] - mnew);
                float rs = p0 + p1;
#pragma unroll
                for (int mm = 1; mm < 16; mm <<= 1)
                    rs += __shfl_xor(rs, mm, 64);
                l_run[qi][r] = l_run[qi][r] * sc + rs;
#pragma unroll
                for (int df = 0; df < 4; ++df)
                    o[qi][df][r] *= sc;
                Ps[wv][qi * 16 + fg * 4 + r][fr]      = (_Float16)p0;
                Ps[wv][qi * 16 + fg * 4 + r][16 + fr] = (_Float16)p1;
            }
        }
        asm volatile("s_waitcnt lgkmcnt(0)" ::: "memory");   // same-wave LDS RAW (cross-lane)
        f16x8_t pa[2];
#pragma unroll
        for (int qi = 0; qi < 2; ++qi)
            pa[qi] = *(const f16x8_t*)&Ps[wv][qi * 16 + fr][fg * 8];
        f16x8_t vb[4];
#pragma unroll
        for (int df = 0; df < 4; ++df)
            vb[df] = *(const f16x8_t*)&Vb[(size_t)(df * 16 + fr) * T_SEQ + k0 + fg * 8];
#pragma unroll
        for (int qi = 0; qi < 2; ++qi)
#pragma unroll
            for (int df = 0; df < 4; ++df)
                o[qi][df] = __builtin_amdgcn_mfma_f32_16x16x32_f16(pa[qi], vb[df], o[qi][df], 0, 0, 0);
    }
    // epilogue: normalize, write (B,T,H*D) fp16
#pragma unroll
    for (int qi = 0; qi < 2; ++qi)
#pragma unroll
        for (int r = 0; r < 4; ++r) {
            const float inv = 1.f / l_run[qi][r];
            const int row = b * T_SEQ + q0 + qi * 16 + fg * 4 + r;
#pragma unroll
            for (int df = 0; df < 4; ++df) {
                const int col = h * HD + df * 16 + fr;
                AO[(size_t)row * CDIM + col] = (_Float16)(o[qi][df][r] * inv);
            }
        }
}

extern "C" void kernel_launch(void* const* d_in, const int* in_sizes, int n_in,
                              void* d_out, int out_size, void* d_ws, size_t ws_size,
                              hipStream_t stream) {
    const float* x    = (const float*)d_in[0];
    const float* mask = (const float*)d_in[1];
    const float* Wq   = (const float*)d_in[2];
    const float* bq   = (const float*)d_in[3];
    const float* Wk   = (const float*)d_in[4];
    const float* bk   = (const float*)d_in[5];
    const float* Wv   = (const float*)d_in[6];
    const float* bv   = (const float*)d_in[7];
    const float* Wo   = (const float*)d_in[8];
    const float* bo   = (const float*)d_in[9];
    float* out = (float*)d_out;

    char* ws = (char*)d_ws;
    _Float16* xh    = (_Float16*)(ws);                    // 4096x1024  (8MB) -- reused as AO
    _Float16* Wqkvh = (_Float16*)(ws + (8u  << 20));      // 3072x1024  (6MB)
    _Float16* Woh   = (_Float16*)(ws + (14u << 20));      // 1024x1024  (2MB)
    _Float16* Qp    = (_Float16*)(ws + (16u << 20));      // (B,H,T,D)  (8MB)
    _Float16* Kp    = (_Float16*)(ws + (24u << 20));      // (B,H,T,D)  (8MB)
    _Float16* Vtp   = (_Float16*)(ws + (32u << 20));      // (B,H,D,T)  (8MB)
    int* mflag      = (int*)(ws + (40u << 20));
    _Float16* AO    = xh;   // alias: x consumed by QKV GEMM before attn writes AO

    hipMemsetAsync(mflag, 0, 4, stream);
    cvt_f32_f16<<<4096, 256, 0, stream>>>(x, xh, NTOK * CDIM / 4);
    cvt_f32_f16<<<1024, 256, 0, stream>>>(Wq, Wqkvh,                   CDIM * CDIM / 4);
    cvt_f32_f16<<<1024, 256, 0, stream>>>(Wk, Wqkvh + CDIM * CDIM,     CDIM * CDIM / 4);
    cvt_f32_f16<<<1024, 256, 0, stream>>>(Wv, Wqkvh + 2 * CDIM * CDIM, CDIM * CDIM / 4);
    cvt_f32_f16<<<1024, 256, 0, stream>>>(Wo, Woh, CDIM * CDIM / 4);
    mask_flag_k<<<512, 256, 0, stream>>>(mask, T_SEQ * T_SEQ / 4, mflag);

    gemm_f16<0><<<dim3(32, 24), 256, 0, stream>>>(xh, Wqkvh, bq, bk, bv,
                                                  Qp, Kp, Vtp, nullptr);
    attn_f16<<<dim3(16, 32), 256, 0, stream>>>(Qp, Kp, Vtp, mask, mflag, AO);
    gemm_f16<1><<<dim3(32, 8), 256, 0, stream>>>(AO, Woh, bo, nullptr, nullptr,
                                                 nullptr, nullptr, nullptr, out);
}

// Round 2
// 147.276 us; speedup vs baseline: 1.5409x; 1.5409x over previous
//
#include <hip/hip_runtime.h>
#include <hip/hip_bf16.h>
#include <stdint.h>

typedef _Float16 f16x8_t __attribute__((ext_vector_type(8)));
typedef _Float16 f16x4_t __attribute__((ext_vector_type(4)));
typedef float    f32x4_t __attribute__((ext_vector_type(4)));

#define T_SEQ 2048
#define NH    16
#define HD    64
#define CDIM  1024
#define NTOK  4096          // B*T
#define SCALE_F 0.125f      // 1/sqrt(64)

// ---------- async global->LDS, 16B per lane ----------
__device__ __forceinline__ void async_ld16(void* lds, const void* g) {
    __builtin_amdgcn_global_load_lds(
        (const __attribute__((address_space(1))) uint32_t*)g,
        (__attribute__((address_space(3))) uint32_t*)lds, 16, 0, 0);
}

// ---------- fp32 -> fp16 convert (vector x4) ----------
__global__ __launch_bounds__(256) void cvt_f32_f16(const float* __restrict__ src,
                                                   _Float16* __restrict__ dst, int n4) {
    int i = blockIdx.x * blockDim.x + threadIdx.x;
    if (i < n4) {
        float4 v = ((const float4*)src)[i];
        f16x4_t h;
        h[0] = (_Float16)v.x; h[1] = (_Float16)v.y;
        h[2] = (_Float16)v.z; h[3] = (_Float16)v.w;
        ((f16x4_t*)dst)[i] = h;
    }
}

// ---------- mask nonzero flag ----------
__global__ __launch_bounds__(256) void mask_flag_k(const float* __restrict__ mask, int n4,
                                                   int* __restrict__ flag) {
    int i = blockIdx.x * blockDim.x + threadIdx.x;
    int stride = gridDim.x * blockDim.x;
    int any = 0;
    for (; i < n4; i += stride) {
        float4 v = ((const float4*)mask)[i];
        any |= (v.x != 0.f) | (v.y != 0.f) | (v.z != 0.f) | (v.w != 0.f);
    }
    if (any) atomicOr(flag, 1);
}

// ---------- GEMM: C[M,N] = A[M,K] * B[N,K]^T (+bias) ----------
// MODE 0: QKV projection, N=3072, scatter to Q,K (B,H,T,D) and V^T (B,H,D,T), fp16 out
// MODE 1: out projection, N=1024, fp32 out to d_out
template<int MODE>
__global__ __launch_bounds__(256)
void gemm_f16(const _Float16* __restrict__ Ag, const _Float16* __restrict__ Bg,
              const float* __restrict__ b0, const float* __restrict__ b1,
              const float* __restrict__ b2,
              _Float16* __restrict__ Qo, _Float16* __restrict__ Ko,
              _Float16* __restrict__ Vto, float* __restrict__ Fo)
{
    __shared__ _Float16 sA[128 * 32];
    __shared__ _Float16 sB[128 * 32];
    const int K = CDIM;
    const int tid  = threadIdx.x;
    const int lane = tid & 63, wv = tid >> 6;
    const int wr = wv >> 1, wc = wv & 1;
    const int rowA0 = blockIdx.x * 128;
    const int rowB0 = blockIdx.y * 128;
    const int srow = lane >> 2;          // staging row within 16-row wave chunk
    const int scol = (lane & 3) * 8;     // staging col (halves)
    const int fr = lane & 15, fg = lane >> 4;
    f32x4_t acc[4][4] = {};

    for (int k0 = 0; k0 < K; k0 += 32) {
#pragma unroll
        for (int i = 0; i < 2; ++i) {
            const int eoff = i * 2048 + wv * 512;       // halves, wave-uniform LDS base
            const int r = (eoff >> 5) + srow;           // tile row 0..127
            async_ld16(&sA[eoff], Ag + (size_t)(rowA0 + r) * K + k0 + scol);
            async_ld16(&sB[eoff], Bg + (size_t)(rowB0 + r) * K + k0 + scol);
        }
        __syncthreads();
        f16x8_t a[4], b[4];
#pragma unroll
        for (int mi = 0; mi < 4; ++mi)
            a[mi] = *(const f16x8_t*)&sA[(wr * 64 + mi * 16 + fr) * 32 + fg * 8];
#pragma unroll
        for (int ni = 0; ni < 4; ++ni)
            b[ni] = *(const f16x8_t*)&sB[(wc * 64 + ni * 16 + fr) * 32 + fg * 8];
#pragma unroll
        for (int mi = 0; mi < 4; ++mi)
#pragma unroll
            for (int ni = 0; ni < 4; ++ni)
                acc[mi][ni] = __builtin_amdgcn_mfma_f32_16x16x32_f16(a[mi], b[ni], acc[mi][ni], 0, 0, 0);
        __syncthreads();
    }

#pragma unroll
    for (int mi = 0; mi < 4; ++mi) {
#pragma unroll
        for (int ni = 0; ni < 4; ++ni) {
            const int col = rowB0 + wc * 64 + ni * 16 + fr;
#pragma unroll
            for (int r = 0; r < 4; ++r) {
                const int row = rowA0 + wr * 64 + mi * 16 + fg * 4 + r;
                float v = acc[mi][ni][r];
                if (MODE == 0) {
                    const int which = col >> 10, cc = col & 1023;
                    const float* bp = (which == 0) ? b0 : ((which == 1) ? b1 : b2);
                    v += bp[cc];
                    const int bb = row >> 11, t = row & (T_SEQ - 1);
                    const int h = cc >> 6, d = cc & 63;
                    const int bh = bb * NH + h;
                    if (which == 0)
                        Qo[((size_t)bh * T_SEQ + t) * HD + d] = (_Float16)(v * SCALE_F);
                    else if (which == 1)
                        Ko[((size_t)bh * T_SEQ + t) * HD + d] = (_Float16)v;
                    else
                        Vto[((size_t)bh * HD + d) * T_SEQ + t] = (_Float16)v;
                } else {
                    Fo[(size_t)row * CDIM + col] = v + b0[col];
                }
            }
        }
    }
}

// ---------- flash attention, fp16, swapped QK^T, online softmax ----------
// grid (T/128, B*H), 512 threads (8 waves); each wave owns 16 q-rows; KV tile = 64
// K/V staged in LDS (double-buffered) via global_load_lds with XOR-swizzled source.
__global__ __launch_bounds__(512)
void attn_f16(const _Float16* __restrict__ Q, const _Float16* __restrict__ Kg,
              const _Float16* __restrict__ Vt, const float* __restrict__ mask,
              const int* __restrict__ mflag, _Float16* __restrict__ AO)
{
    __shared__ __align__(16) _Float16 sK[2][4096];     // [64 k][64 d], swizzled
    __shared__ __align__(16) _Float16 sV[2][4096];     // [64 d][64 t], swizzled
    __shared__ __align__(16) _Float16 Ps[8][16][72];   // per-wave P: [q][k], pad->stride 72

    const int tid = threadIdx.x;
    const int lane = tid & 63, wv = tid >> 6;
    const int fr = lane & 15, fg = lane >> 4;
    const int bh = blockIdx.y;
    const int b = bh >> 4, h = bh & (NH - 1);
    const int q0 = blockIdx.x * 128 + wv * 16;
    const _Float16* Qb = Q  + (size_t)bh * T_SEQ * HD;
    const _Float16* Kb = Kg + (size_t)bh * T_SEQ * HD;
    const _Float16* Vb = Vt + (size_t)bh * HD * T_SEQ;

    // staging geometry: 512 threads x 16B = 8KB tile; each wave fills 8 rows of 128B
    const int srow = wv * 8 + ((lane >> 3) & 7);          // tile row 0..63
    const int ssw  = ((lane & 7) * 8) ^ ((srow & 7) << 3); // swizzled col (halves)
    const int rsw  = (fr & 7) << 3;                        // read-side XOR (halves)

    // Q fragments (B-operand: col=q=fr, k-chunk=fg*8), Q pre-scaled by 1/sqrt(D)
    f16x8_t qf[2];
#pragma unroll
    for (int dc = 0; dc < 2; ++dc)
        qf[dc] = *(const f16x8_t*)&Qb[(size_t)(q0 + fr) * HD + dc * 32 + fg * 8];

    f32x4_t o[4] = {};                 // O[q=fg*4+r][d=df*16+fr]
    float m_run = -1e30f, l_run = 0.f; // stats for q = fr (replicated over fg)
    const int mf = mflag[0];

    // prologue: stage tile 0 into buf 0
    async_ld16(&sK[0][wv * 512], Kb + (size_t)srow * HD + ssw);
    async_ld16(&sV[0][wv * 512], Vb + (size_t)srow * T_SEQ + 0 + ssw);

    for (int t = 0; t < T_SEQ / 64; ++t) {
        const int k0 = t * 64, cur = t & 1;
        __syncthreads();   // drains vmcnt (stage of buf[cur] complete everywhere)
        if (t + 1 < T_SEQ / 64) {
            const int kn = k0 + 64, nb = cur ^ 1;
            async_ld16(&sK[nb][wv * 512], Kb + (size_t)(kn + srow) * HD + ssw);
            async_ld16(&sV[nb][wv * 512], Vb + (size_t)srow * T_SEQ + kn + ssw);
        }

        // ---- S^T = K * Q^T : lane holds S[k=kt*16+fg*4+r][q=fr] ----
        f32x4_t s[4];
#pragma unroll
        for (int kt = 0; kt < 4; ++kt) {
            const int krow = (kt * 16 + fr) * 64;
            f16x8_t kf0 = *(const f16x8_t*)&sK[cur][krow + ((fg * 8) ^ rsw)];
            f16x8_t kf1 = *(const f16x8_t*)&sK[cur][krow + ((32 + fg * 8) ^ rsw)];
            f32x4_t z = {};
            z = __builtin_amdgcn_mfma_f32_16x16x32_f16(kf0, qf[0], z, 0, 0, 0);
            s[kt] = __builtin_amdgcn_mfma_f32_16x16x32_f16(kf1, qf[1], z, 0, 0, 0);
        }
        if (mf) {
            const float* mrow = mask + (size_t)(q0 + fr) * T_SEQ + k0;
#pragma unroll
            for (int kt = 0; kt < 4; ++kt)
#pragma unroll
                for (int r = 0; r < 4; ++r)
                    s[kt][r] += mrow[kt * 16 + fg * 4 + r];
        }

        // ---- online softmax (per-lane row slice, 2 cross-lane steps) ----
        float tmax = -1e30f;
#pragma unroll
        for (int kt = 0; kt < 4; ++kt) {
            float a = fmaxf(fmaxf(s[kt][0], s[kt][1]), fmaxf(s[kt][2], s[kt][3]));
            tmax = fmaxf(tmax, a);
        }
        tmax = fmaxf(tmax, __shfl_xor(tmax, 16, 64));
        tmax = fmaxf(tmax, __shfl_xor(tmax, 32, 64));

        if (!__all(tmax <= m_run + 5.0f)) {           // defer-max (T13)
            const float mnew = fmaxf(m_run, tmax);
            const float sc = __expf(m_run - mnew);
            m_run = mnew;
            float scq[4];
#pragma unroll
            for (int r = 0; r < 4; ++r)
                scq[r] = __shfl(sc, fg * 4 + r, 64);  // redistribute to O layout
#pragma unroll
            for (int df = 0; df < 4; ++df)
#pragma unroll
                for (int r = 0; r < 4; ++r)
                    o[df][r] *= scq[r];
            l_run *= sc;
        }

        float rs = 0.f;
#pragma unroll
        for (int kt = 0; kt < 4; ++kt) {
#pragma unroll
            for (int r = 0; r < 4; ++r) {
                s[kt][r] = __expf(s[kt][r] - m_run);
                rs += s[kt][r];
            }
            f16x4_t hp;
            hp[0] = (_Float16)s[kt][0]; hp[1] = (_Float16)s[kt][1];
            hp[2] = (_Float16)s[kt][2]; hp[3] = (_Float16)s[kt][3];
            *(f16x4_t*)&Ps[wv][fr][kt * 16 + fg * 4] = hp;
        }
        rs += __shfl_xor(rs, 16, 64);
        rs += __shfl_xor(rs, 32, 64);
        l_run += rs;

        asm volatile("s_waitcnt lgkmcnt(0)" ::: "memory");  // wave-internal P RAW
        __builtin_amdgcn_sched_barrier(0);

        // ---- O += P * V ----
#pragma unroll
        for (int kt2 = 0; kt2 < 2; ++kt2) {
            f16x8_t pa = *(const f16x8_t*)&Ps[wv][fr][kt2 * 32 + fg * 8];
#pragma unroll
            for (int df = 0; df < 4; ++df) {
                f16x8_t vb = *(const f16x8_t*)&sV[cur][(df * 16 + fr) * 64 + ((kt2 * 32 + fg * 8) ^ rsw)];
                o[df] = __builtin_amdgcn_mfma_f32_16x16x32_f16(pa, vb, o[df], 0, 0, 0);
            }
        }
    }

    // ---- epilogue: normalize, write (B,T,H*D) fp16 ----
    float lq[4];
#pragma unroll
    for (int r = 0; r < 4; ++r)
        lq[r] = __shfl(l_run, fg * 4 + r, 64);
#pragma unroll
    for (int r = 0; r < 4; ++r) {
        const float inv = 1.f / lq[r];
        const size_t row = (size_t)(b * T_SEQ + q0 + fg * 4 + r);
#pragma unroll
        for (int df = 0; df < 4; ++df)
            AO[row * CDIM + h * HD + df * 16 + fr] = (_Float16)(o[df][r] * inv);
    }
}

extern "C" void kernel_launch(void* const* d_in, const int* in_sizes, int n_in,
                              void* d_out, int out_size, void* d_ws, size_t ws_size,
                              hipStream_t stream) {
    const float* x    = (const float*)d_in[0];
    const float* mask = (const float*)d_in[1];
    const float* Wq   = (const float*)d_in[2];
    const float* bq   = (const float*)d_in[3];
    const float* Wk   = (const float*)d_in[4];
    const float* bk   = (const float*)d_in[5];
    const float* Wv   = (const float*)d_in[6];
    const float* bv   = (const float*)d_in[7];
    const float* Wo   = (const float*)d_in[8];
    const float* bo   = (const float*)d_in[9];
    float* out = (float*)d_out;

    char* ws = (char*)d_ws;
    _Float16* xh    = (_Float16*)(ws);                    // 4096x1024  (8MB) -- reused as AO
    _Float16* Wqkvh = (_Float16*)(ws + (8u  << 20));      // 3072x1024  (6MB)
    _Float16* Woh   = (_Float16*)(ws + (14u << 20));      // 1024x1024  (2MB)
    _Float16* Qp    = (_Float16*)(ws + (16u << 20));      // (B,H,T,D)  (8MB)
    _Float16* Kp    = (_Float16*)(ws + (24u << 20));      // (B,H,T,D)  (8MB)
    _Float16* Vtp   = (_Float16*)(ws + (32u << 20));      // (B,H,D,T)  (8MB)
    int* mflag      = (int*)(ws + (40u << 20));
    _Float16* AO    = xh;   // alias: x consumed by QKV GEMM before attn writes AO

    hipMemsetAsync(mflag, 0, 4, stream);
    cvt_f32_f16<<<4096, 256, 0, stream>>>(x, xh, NTOK * CDIM / 4);
    cvt_f32_f16<<<1024, 256, 0, stream>>>(Wq, Wqkvh,                   CDIM * CDIM / 4);
    cvt_f32_f16<<<1024, 256, 0, stream>>>(Wk, Wqkvh + CDIM * CDIM,     CDIM * CDIM / 4);
    cvt_f32_f16<<<1024, 256, 0, stream>>>(Wv, Wqkvh + 2 * CDIM * CDIM, CDIM * CDIM / 4);
    cvt_f32_f16<<<1024, 256, 0, stream>>>(Wo, Woh, CDIM * CDIM / 4);
    mask_flag_k<<<512, 256, 0, stream>>>(mask, T_SEQ * T_SEQ / 4, mflag);

    gemm_f16<0><<<dim3(32, 24), 256, 0, stream>>>(xh, Wqkvh, bq, bk, bv,
                                                  Qp, Kp, Vtp, nullptr);
    attn_f16<<<dim3(16, 32), 512, 0, stream>>>(Qp, Kp, Vtp, mask, mflag, AO);
    gemm_f16<1><<<dim3(32, 8), 256, 0, stream>>>(AO, Woh, bo, nullptr, nullptr,
                                                 nullptr, nullptr, nullptr, out);
}

// Round 3
// 134.444 us; speedup vs baseline: 1.6880x; 1.0954x over previous
//
#include <hip/hip_runtime.h>
#include <hip/hip_bf16.h>
#include <stdint.h>

typedef _Float16 f16x8_t __attribute__((ext_vector_type(8)));
typedef _Float16 f16x4_t __attribute__((ext_vector_type(4)));
typedef float    f32x4_t __attribute__((ext_vector_type(4)));

#define T_SEQ 2048
#define NH    16
#define HD    64
#define CDIM  1024
#define NTOK  4096          // B*T
#define QSCALE 0.18033688011112042f   // (1/sqrt(64)) * log2(e)
#define LOG2E  1.4426950408889634f

// ---------- async global->LDS, 16B per lane ----------
__device__ __forceinline__ void async_ld16(void* lds, const void* g) {
    __builtin_amdgcn_global_load_lds(
        (const __attribute__((address_space(1))) uint32_t*)g,
        (__attribute__((address_space(3))) uint32_t*)lds, 16, 0, 0);
}

// ---------- fused: fp32->fp16 converts (x, Wq,Wk,Wv,Wo) + mask-nonzero flag ----------
__global__ __launch_bounds__(256)
void prep_all(const float* __restrict__ x, const float* __restrict__ Wq,
              const float* __restrict__ Wk, const float* __restrict__ Wv,
              const float* __restrict__ Wo, const float* __restrict__ mask,
              _Float16* __restrict__ xh, _Float16* __restrict__ Wqkvh,
              _Float16* __restrict__ Woh, int* __restrict__ flag)
{
    const int XQ = NTOK * CDIM / 4;     // 1M float4
    const int WQ = CDIM * CDIM / 4;     // 256K float4
    int i = blockIdx.x * 256 + threadIdx.x;
    if (i < XQ + 4 * WQ) {
        const float* s; _Float16* d; int off;
        if (i < XQ) { s = x; d = xh; off = i; }
        else {
            int j = i - XQ; int w = j >> 18; off = j & (WQ - 1);
            s = (w == 0) ? Wq : (w == 1) ? Wk : (w == 2) ? Wv : Wo;
            d = (w == 3) ? Woh : Wqkvh + (size_t)w * CDIM * CDIM;
        }
        float4 v = ((const float4*)s)[off];
        f16x4_t h = {(_Float16)v.x, (_Float16)v.y, (_Float16)v.z, (_Float16)v.w};
        ((f16x4_t*)d)[off] = h;
    } else {
        int off = i - (XQ + 4 * WQ);
        float4 v = ((const float4*)mask)[off];
        if (v.x != 0.f || v.y != 0.f || v.z != 0.f || v.w != 0.f) atomicOr(flag, 1);
    }
}

// ---------- GEMM: C[M,N] = A[M,K] * B[N,K]^T (+bias), 2-phase double-buffered ----------
// MODE 0: QKV projection, scatter Q (scaled, [bh][t][d]) and K/V in attn-chunked layout
// MODE 1: out projection, fp32 out to d_out
template<int MODE>
__global__ __launch_bounds__(256)
void gemm_f16(const _Float16* __restrict__ Ag, const _Float16* __restrict__ Bg,
              const float* __restrict__ b0, const float* __restrict__ b1,
              const float* __restrict__ b2,
              _Float16* __restrict__ Qo, _Float16* __restrict__ Ko,
              _Float16* __restrict__ Vto, float* __restrict__ Fo)
{
    __shared__ _Float16 sA[2][128 * 32];
    __shared__ _Float16 sB[2][128 * 32];
    const int K = CDIM;
    const int tid  = threadIdx.x;
    const int lane = tid & 63, wv = tid >> 6;
    const int wr = wv >> 1, wc = wv & 1;
    const int rowA0 = blockIdx.x * 128;
    const int rowB0 = blockIdx.y * 128;
    const int srow = lane >> 2;          // staging row within 16-row chunk
    const int scol = (lane & 3) * 8;     // staging col (halves)
    const int fr = lane & 15, fg = lane >> 4;
    f32x4_t acc[4][4] = {};

#define STAGE(buf, kk) do {                                                     \
        _Pragma("unroll")                                                       \
        for (int i_ = 0; i_ < 2; ++i_) {                                        \
            const int eoff = i_ * 2048 + wv * 512;                              \
            const int r_ = i_ * 64 + wv * 16 + srow;                            \
            async_ld16(&sA[buf][eoff], Ag + (size_t)(rowA0 + r_) * K + (kk) + scol); \
            async_ld16(&sB[buf][eoff], Bg + (size_t)(rowB0 + r_) * K + (kk) + scol); \
        } } while (0)

    STAGE(0, 0);
    for (int k0 = 0; k0 < K; k0 += 32) {
        const int cur = (k0 >> 5) & 1;
        __syncthreads();                       // buf[cur] staged, prev reads done
        if (k0 + 32 < K) STAGE(cur ^ 1, k0 + 32);
        f16x8_t a[4], b[4];
#pragma unroll
        for (int mi = 0; mi < 4; ++mi)
            a[mi] = *(const f16x8_t*)&sA[cur][(wr * 64 + mi * 16 + fr) * 32 + fg * 8];
#pragma unroll
        for (int ni = 0; ni < 4; ++ni)
            b[ni] = *(const f16x8_t*)&sB[cur][(wc * 64 + ni * 16 + fr) * 32 + fg * 8];
#pragma unroll
        for (int mi = 0; mi < 4; ++mi)
#pragma unroll
            for (int ni = 0; ni < 4; ++ni)
                acc[mi][ni] = __builtin_amdgcn_mfma_f32_16x16x32_f16(a[mi], b[ni], acc[mi][ni], 0, 0, 0);
    }
#undef STAGE

#pragma unroll
    for (int mi = 0; mi < 4; ++mi) {
#pragma unroll
        for (int ni = 0; ni < 4; ++ni) {
            const int col = rowB0 + wc * 64 + ni * 16 + fr;
#pragma unroll
            for (int r = 0; r < 4; ++r) {
                const int row = rowA0 + wr * 64 + mi * 16 + fg * 4 + r;
                float v = acc[mi][ni][r];
                if (MODE == 0) {
                    const int which = col >> 10, cc = col & 1023;
                    const float* bp = (which == 0) ? b0 : ((which == 1) ? b1 : b2);
                    v += bp[cc];
                    const int bb = row >> 11, tt = row & (T_SEQ - 1);
                    const int h = cc >> 6, d = cc & 63;
                    const int bh = bb * NH + h;
                    const size_t tbase = ((size_t)bh * 32 + (tt >> 6)) * 4096;
                    if (which == 0)
                        Qo[((size_t)bh * T_SEQ + tt) * HD + d] = (_Float16)(v * QSCALE);
                    else if (which == 1)   // K chunked: [tile][d/8][t&63][d&7]
                        Ko[tbase + (size_t)(d >> 3) * 512 + (tt & 63) * 8 + (d & 7)] = (_Float16)v;
                    else                   // V chunked: [tile][(t>>3)&7][d][t&7]
                        Vto[tbase + (size_t)((tt >> 3) & 7) * 512 + d * 8 + (tt & 7)] = (_Float16)v;
                } else {
                    Fo[(size_t)row * CDIM + col] = v + b0[col];
                }
            }
        }
    }
}

// ---------- flash attention, fp16, swapped QK^T, log2-domain online softmax ----------
// grid (T/128, B*H), 512 threads (8 waves); wave owns 16 q-rows; KV tile = 64
// K/V staged via global_load_lds from chunked-global layout -> conflict-free ds_read_b128.
__global__ __launch_bounds__(512, 4)
void attn_f16(const _Float16* __restrict__ Q, const _Float16* __restrict__ Kc,
              const _Float16* __restrict__ Vc, const float* __restrict__ mask,
              const int* __restrict__ mflag, _Float16* __restrict__ AO)
{
    __shared__ __align__(16) _Float16 sK[2][4096];   // [8 dchunk][64 k][8]
    __shared__ __align__(16) _Float16 sV[2][4096];   // [8 tchunk][64 d][8]
    __shared__ __align__(16) _Float16 Ps[8][1024];   // per-wave [8 kchunk][16 q][8]

    const int tid = threadIdx.x;
    const int lane = tid & 63, wv = tid >> 6;
    const int fr = lane & 15, fg = lane >> 4;
    const int bh = blockIdx.y;
    const int b = bh >> 4, h = bh & (NH - 1);
    const int q0 = blockIdx.x * 128 + wv * 16;
    const _Float16* Qb  = Q  + (size_t)bh * T_SEQ * HD;
    const _Float16* Kbh = Kc + (size_t)bh * (T_SEQ * HD);
    const _Float16* Vbh = Vc + (size_t)bh * (T_SEQ * HD);
    const int soff = wv * 512 + lane * 8;   // halves; lane*16B contiguous

    f16x8_t qf[2];   // Q pre-scaled by 1/sqrt(D)*log2e
#pragma unroll
    for (int dc = 0; dc < 2; ++dc)
        qf[dc] = *(const f16x8_t*)&Qb[(size_t)(q0 + fr) * HD + dc * 32 + fg * 8];

    f32x4_t o[4] = {};                 // O[q=fg*4+r][d=df*16+fr]
    float m_run = -1e30f, l_run = 0.f; // stats for q = fr (log2 domain)
    const int mf = mflag[0];

    async_ld16(&sK[0][wv * 512], Kbh + soff);
    async_ld16(&sV[0][wv * 512], Vbh + soff);

    for (int t = 0; t < T_SEQ / 64; ++t) {
        const int cur = t & 1;
        __syncthreads();                       // buf[cur] ready (drains vmcnt)
        if (t + 1 < T_SEQ / 64) {
            async_ld16(&sK[cur ^ 1][wv * 512], Kbh + (t + 1) * 4096 + soff);
            async_ld16(&sV[cur ^ 1][wv * 512], Vbh + (t + 1) * 4096 + soff);
        }

        // ---- S^T = K * Q^T : lane holds S[k=kt*16+fg*4+r][q=fr] ----
        f32x4_t s[4];
        __builtin_amdgcn_s_setprio(1);
#pragma unroll
        for (int kt = 0; kt < 4; ++kt) {
            f16x8_t kf0 = *(const f16x8_t*)&sK[cur][fg * 512       + (kt * 16 + fr) * 8];
            f16x8_t kf1 = *(const f16x8_t*)&sK[cur][(4 + fg) * 512 + (kt * 16 + fr) * 8];
            f32x4_t z = {};
            z     = __builtin_amdgcn_mfma_f32_16x16x32_f16(kf0, qf[0], z, 0, 0, 0);
            s[kt] = __builtin_amdgcn_mfma_f32_16x16x32_f16(kf1, qf[1], z, 0, 0, 0);
        }
        __builtin_amdgcn_s_setprio(0);

        // hoist V fragment reads; LDS latency hides under softmax VALU
        f16x8_t vb[2][4];
#pragma unroll
        for (int kt2 = 0; kt2 < 2; ++kt2)
#pragma unroll
            for (int df = 0; df < 4; ++df)
                vb[kt2][df] = *(const f16x8_t*)&sV[cur][(kt2 * 4 + fg) * 512 + (df * 16 + fr) * 8];

        if (mf) {
            const float* mrow = mask + (size_t)(q0 + fr) * T_SEQ + t * 64;
#pragma unroll
            for (int kt = 0; kt < 4; ++kt)
#pragma unroll
                for (int r = 0; r < 4; ++r)
                    s[kt][r] += mrow[kt * 16 + fg * 4 + r] * LOG2E;
        }

        // ---- online softmax (log2 domain; 2 cross-lane steps) ----
        float tmax = -1e30f;
#pragma unroll
        for (int kt = 0; kt < 4; ++kt)
            tmax = fmaxf(tmax, fmaxf(fmaxf(s[kt][0], s[kt][1]), fmaxf(s[kt][2], s[kt][3])));
        tmax = fmaxf(tmax, __shfl_xor(tmax, 16, 64));
        tmax = fmaxf(tmax, __shfl_xor(tmax, 32, 64));

        if (!__all(tmax <= m_run + 8.0f)) {           // defer-max (T13)
            const float mnew = fmaxf(m_run, tmax);
            const float sc = __builtin_amdgcn_exp2f(m_run - mnew);
            m_run = mnew;
            float scq[4];
#pragma unroll
            for (int r = 0; r < 4; ++r)
                scq[r] = __shfl(sc, fg * 4 + r, 64);
#pragma unroll
            for (int df = 0; df < 4; ++df)
#pragma unroll
                for (int r = 0; r < 4; ++r)
                    o[df][r] *= scq[r];
            l_run *= sc;
        }

        float rs = 0.f;
#pragma unroll
        for (int kt = 0; kt < 4; ++kt) {
            f16x4_t hp;
#pragma unroll
            for (int r = 0; r < 4; ++r) {
                const float p = __builtin_amdgcn_exp2f(s[kt][r] - m_run);
                rs += p;
                hp[r] = (_Float16)p;
            }
            // P[k][q=fr] -> chunk k>>3, elem k&7
            *(f16x4_t*)&Ps[wv][(kt * 2 + (fg >> 1)) * 128 + fr * 8 + (fg & 1) * 4] = hp;
        }
        rs += __shfl_xor(rs, 16, 64);
        rs += __shfl_xor(rs, 32, 64);
        l_run += rs;

        asm volatile("s_waitcnt lgkmcnt(0)" ::: "memory");  // cross-lane P RAW
        __builtin_amdgcn_sched_barrier(0);

        // ---- O += P * V ----
        __builtin_amdgcn_s_setprio(1);
#pragma unroll
        for (int kt2 = 0; kt2 < 2; ++kt2) {
            f16x8_t pa = *(const f16x8_t*)&Ps[wv][(kt2 * 4 + fg) * 128 + fr * 8];
#pragma unroll
            for (int df = 0; df < 4; ++df)
                o[df] = __builtin_amdgcn_mfma_f32_16x16x32_f16(pa, vb[kt2][df], o[df], 0, 0, 0);
        }
        __builtin_amdgcn_s_setprio(0);
    }

    // ---- epilogue: normalize, write (B,T,H*D) fp16 ----
    float lq[4];
#pragma unroll
    for (int r = 0; r < 4; ++r)
        lq[r] = __shfl(l_run, fg * 4 + r, 64);
#pragma unroll
    for (int r = 0; r < 4; ++r) {
        const float inv = 1.f / lq[r];
        const size_t row = (size_t)(b * T_SEQ + q0 + fg * 4 + r);
#pragma unroll
        for (int df = 0; df < 4; ++df)
            AO[row * CDIM + h * HD + df * 16 + fr] = (_Float16)(o[df][r] * inv);
    }
}

extern "C" void kernel_launch(void* const* d_in, const int* in_sizes, int n_in,
                              void* d_out, int out_size, void* d_ws, size_t ws_size,
                              hipStream_t stream) {
    const float* x    = (const float*)d_in[0];
    const float* mask = (const float*)d_in[1];
    const float* Wq   = (const float*)d_in[2];
    const float* bq   = (const float*)d_in[3];
    const float* Wk   = (const float*)d_in[4];
    const float* bk   = (const float*)d_in[5];
    const float* Wv   = (const float*)d_in[6];
    const float* bv   = (const float*)d_in[7];
    const float* Wo   = (const float*)d_in[8];
    const float* bo   = (const float*)d_in[9];
    float* out = (float*)d_out;

    char* ws = (char*)d_ws;
    _Float16* xh    = (_Float16*)(ws);                    // 4096x1024  (8MB) -- reused as AO
    _Float16* Wqkvh = (_Float16*)(ws + (8u  << 20));      // 3072x1024  (6MB)
    _Float16* Woh   = (_Float16*)(ws + (14u << 20));      // 1024x1024  (2MB)
    _Float16* Qp    = (_Float16*)(ws + (16u << 20));      // (B,H,T,D)  (8MB)
    _Float16* Kc    = (_Float16*)(ws + (24u << 20));      // chunked    (8MB)
    _Float16* Vc    = (_Float16*)(ws + (32u << 20));      // chunked    (8MB)
    int* mflag      = (int*)(ws + (40u << 20));
    _Float16* AO    = xh;   // alias: x consumed by QKV GEMM before attn writes AO

    hipMemsetAsync(mflag, 0, 4, stream);
    prep_all<<<12288, 256, 0, stream>>>(x, Wq, Wk, Wv, Wo, mask, xh, Wqkvh, Woh, mflag);
    gemm_f16<0><<<dim3(32, 24), 256, 0, stream>>>(xh, Wqkvh, bq, bk, bv,
                                                  Qp, Kc, Vc, nullptr);
    attn_f16<<<dim3(16, 32), 512, 0, stream>>>(Qp, Kc, Vc, mask, mflag, AO);
    gemm_f16<1><<<dim3(32, 8), 256, 0, stream>>>(AO, Woh, bo, nullptr, nullptr,
                                                 nullptr, nullptr, nullptr, out);
}

// Round 4
// 128.476 us; speedup vs baseline: 1.7664x; 1.0465x over previous
//
#include <hip/hip_runtime.h>
#include <hip/hip_bf16.h>
#include <stdint.h>

typedef _Float16 f16x8_t __attribute__((ext_vector_type(8)));
typedef _Float16 f16x4_t __attribute__((ext_vector_type(4)));
typedef float    f32x4_t __attribute__((ext_vector_type(4)));

#define T_SEQ 2048
#define NH    16
#define HD    64
#define CDIM  1024
#define NTOK  4096          // B*T
#define QSCALE 0.18033688011112042f   // (1/sqrt(64)) * log2(e)
#define LOG2E  1.4426950408889634f

// ---------- async global->LDS, 16B per lane ----------
__device__ __forceinline__ void async_ld16(void* lds, const void* g) {
    __builtin_amdgcn_global_load_lds(
        (const __attribute__((address_space(1))) uint32_t*)g,
        (__attribute__((address_space(3))) uint32_t*)lds, 16, 0, 0);
}

// ---------- fused: fp32->fp16 converts (x, Wq,Wk,Wv,Wo) + mask-nonzero flag ----------
__global__ __launch_bounds__(256)
void prep_all(const float* __restrict__ x, const float* __restrict__ Wq,
              const float* __restrict__ Wk, const float* __restrict__ Wv,
              const float* __restrict__ Wo, const float* __restrict__ mask,
              _Float16* __restrict__ xh, _Float16* __restrict__ Wqkvh,
              _Float16* __restrict__ Woh, int* __restrict__ flag)
{
    const int XQ = NTOK * CDIM / 4;     // 1M float4
    const int WQ = CDIM * CDIM / 4;     // 256K float4
    int i = blockIdx.x * 256 + threadIdx.x;
    if (i < XQ + 4 * WQ) {
        const float* s; _Float16* d; int off;
        if (i < XQ) { s = x; d = xh; off = i; }
        else {
            int j = i - XQ; int w = j >> 18; off = j & (WQ - 1);
            s = (w == 0) ? Wq : (w == 1) ? Wk : (w == 2) ? Wv : Wo;
            d = (w == 3) ? Woh : Wqkvh + (size_t)w * CDIM * CDIM;
        }
        float4 v = ((const float4*)s)[off];
        f16x4_t h = {(_Float16)v.x, (_Float16)v.y, (_Float16)v.z, (_Float16)v.w};
        ((f16x4_t*)d)[off] = h;
    } else {
        int off = i - (XQ + 4 * WQ);
        float4 v = ((const float4*)mask)[off];
        if (v.x != 0.f || v.y != 0.f || v.z != 0.f || v.w != 0.f) atomicOr(flag, 1);
    }
}

// ---------- GEMM (C^T orientation): C[cc][tok] = A[cc][K] * B[tok][K]^T ----------
// A = weights (rows = output channel cc), B = activations (rows = token).
// Lane holds 4 CONSECUTIVE cc values per acc reg -> vectorized epilogue stores.
// MODE 0: QKV projection (A rows 3072), scatter Q [bh][t][d] (scaled) and K/V attn-chunked, fp16
// MODE 1: out projection (A rows 1024), fp32 [tok][cc] to d_out
template<int MODE>
__global__ __launch_bounds__(256)
void gemm_f16(const _Float16* __restrict__ Ag, const _Float16* __restrict__ Bg,
              const float* __restrict__ b0, const float* __restrict__ b1,
              const float* __restrict__ b2,
              _Float16* __restrict__ Qo, _Float16* __restrict__ Ko,
              _Float16* __restrict__ Vto, float* __restrict__ Fo)
{
    __shared__ _Float16 sA[2][128 * 32];
    __shared__ _Float16 sB[2][128 * 32];
    const int K = CDIM;
    const int NBX = (MODE == 0) ? 24 : 8;          // blocks along cc
    const int NWG = NBX * 32;
    const int tid  = threadIdx.x;
    const int lane = tid & 63, wv = tid >> 6;
    const int wr = wv >> 1, wc = wv & 1;
    // XCD-aware bijective swizzle (nwg % 8 == 0)
    const int bid = blockIdx.x;
    const int swz = (bid & 7) * (NWG / 8) + (bid >> 3);
    const int rowA0 = (swz % NBX) * 128;           // cc block
    const int rowB0 = (swz / NBX) * 128;           // token block
    const int srow = lane >> 2;
    const int scol = (lane & 3) * 8;
    const int fr = lane & 15, fg = lane >> 4;
    f32x4_t acc[4][4] = {};

#define STAGE(buf, kk) do {                                                     \
        _Pragma("unroll")                                                       \
        for (int i_ = 0; i_ < 2; ++i_) {                                        \
            const int eoff = i_ * 2048 + wv * 512;                              \
            const int r_ = i_ * 64 + wv * 16 + srow;                            \
            async_ld16(&sA[buf][eoff], Ag + (size_t)(rowA0 + r_) * K + (kk) + scol); \
            async_ld16(&sB[buf][eoff], Bg + (size_t)(rowB0 + r_) * K + (kk) + scol); \
        } } while (0)

    STAGE(0, 0);
    for (int k0 = 0; k0 < K; k0 += 32) {
        const int cur = (k0 >> 5) & 1;
        __syncthreads();                       // buf[cur] staged, prev reads done
        if (k0 + 32 < K) STAGE(cur ^ 1, k0 + 32);
        f16x8_t a[4], b[4];
#pragma unroll
        for (int mi = 0; mi < 4; ++mi)
            a[mi] = *(const f16x8_t*)&sA[cur][(wr * 64 + mi * 16 + fr) * 32 + fg * 8];
#pragma unroll
        for (int ni = 0; ni < 4; ++ni)
            b[ni] = *(const f16x8_t*)&sB[cur][(wc * 64 + ni * 16 + fr) * 32 + fg * 8];
#pragma unroll
        for (int mi = 0; mi < 4; ++mi)
#pragma unroll
            for (int ni = 0; ni < 4; ++ni)
                acc[mi][ni] = __builtin_amdgcn_mfma_f32_16x16x32_f16(a[mi], b[ni], acc[mi][ni], 0, 0, 0);
    }
#undef STAGE

    // epilogue: row = cc (4 consecutive per lane over regs), col = token (fr)
    if (MODE == 0) {
        const int which = rowA0 >> 10;                  // block-uniform: 0=Q 1=K 2=V
        const float* bp = (which == 0) ? b0 : ((which == 1) ? b1 : b2);
#pragma unroll
        for (int mi = 0; mi < 4; ++mi) {
            const int cc = (rowA0 & 1023) + wr * 64 + mi * 16 + fg * 4;  // within 1024
            const float4 bv = *(const float4*)&bp[cc];
            const int h = cc >> 6, d0 = cc & 63;
#pragma unroll
            for (int ni = 0; ni < 4; ++ni) {
                const int tok = rowB0 + wc * 64 + ni * 16 + fr;
                const int bh = (tok >> 11) * NH + h, tt = tok & (T_SEQ - 1);
                const float v0 = acc[mi][ni][0] + bv.x, v1 = acc[mi][ni][1] + bv.y;
                const float v2 = acc[mi][ni][2] + bv.z, v3 = acc[mi][ni][3] + bv.w;
                if (which == 0) {
                    f16x4_t hq = {(_Float16)(v0 * QSCALE), (_Float16)(v1 * QSCALE),
                                  (_Float16)(v2 * QSCALE), (_Float16)(v3 * QSCALE)};
                    *(f16x4_t*)&Qo[((size_t)bh * T_SEQ + tt) * HD + d0] = hq;
                } else if (which == 1) {   // K chunked: [tile][d>>3][t&63][d&7]
                    f16x4_t hk = {(_Float16)v0, (_Float16)v1, (_Float16)v2, (_Float16)v3};
                    *(f16x4_t*)&Ko[((size_t)bh * 32 + (tt >> 6)) * 4096 +
                                   (d0 >> 3) * 512 + (tt & 63) * 8 + (d0 & 7)] = hk;
                } else {                   // V chunked: [tile][(t>>3)&7][d][t&7]
                    const size_t vb_ = ((size_t)bh * 32 + (tt >> 6)) * 4096 +
                                       (size_t)((tt >> 3) & 7) * 512 + (tt & 7);
                    Vto[vb_ + (d0 + 0) * 8] = (_Float16)v0;
                    Vto[vb_ + (d0 + 1) * 8] = (_Float16)v1;
                    Vto[vb_ + (d0 + 2) * 8] = (_Float16)v2;
                    Vto[vb_ + (d0 + 3) * 8] = (_Float16)v3;
                }
            }
        }
    } else {
#pragma unroll
        for (int mi = 0; mi < 4; ++mi) {
            const int cc = rowA0 + wr * 64 + mi * 16 + fg * 4;
            const float4 bv = *(const float4*)&b0[cc];
#pragma unroll
            for (int ni = 0; ni < 4; ++ni) {
                const int tok = rowB0 + wc * 64 + ni * 16 + fr;
                float4 ov = {acc[mi][ni][0] + bv.x, acc[mi][ni][1] + bv.y,
                             acc[mi][ni][2] + bv.z, acc[mi][ni][3] + bv.w};
                *(float4*)&Fo[(size_t)tok * CDIM + cc] = ov;   // 16 full 64B lines/instr
            }
        }
    }
}

// ---------- flash attention, fp16, swapped QK^T, log2-domain online softmax ----------
// 1D grid 512 (XCD-swizzled), 512 threads (8 waves); wave owns 16 q-rows; KV tile = 64
// l_run tracked via ones-MFMA accumulator (same rescale recurrence as O).
__global__ __launch_bounds__(512, 4)
void attn_f16(const _Float16* __restrict__ Q, const _Float16* __restrict__ Kc,
              const _Float16* __restrict__ Vc, const float* __restrict__ mask,
              const int* __restrict__ mflag, _Float16* __restrict__ AO)
{
    __shared__ __align__(16) _Float16 sK[2][4096];   // [8 dchunk][64 k][8]
    __shared__ __align__(16) _Float16 sV[2][4096];   // [8 tchunk][64 d][8]
    __shared__ __align__(16) _Float16 Ps[8][1024];   // per-wave [8 kchunk][16 q][8]

    const int tid = threadIdx.x;
    const int lane = tid & 63, wv = tid >> 6;
    const int fr = lane & 15, fg = lane >> 4;
    const int bid = blockIdx.x;
    const int swz = (bid & 7) * 64 + (bid >> 3);     // bijective, 512 % 8 == 0
    const int qx = swz & 15, bh = swz >> 4;
    const int b = bh >> 4, h = bh & (NH - 1);
    const int q0 = qx * 128 + wv * 16;
    const _Float16* Qb  = Q  + (size_t)bh * T_SEQ * HD;
    const _Float16* Kbh = Kc + (size_t)bh * (T_SEQ * HD);
    const _Float16* Vbh = Vc + (size_t)bh * (T_SEQ * HD);
    const int soff = wv * 512 + lane * 8;   // halves; lane*16B contiguous

    f16x8_t qf[2];   // Q pre-scaled by 1/sqrt(D)*log2e
#pragma unroll
    for (int dc = 0; dc < 2; ++dc)
        qf[dc] = *(const f16x8_t*)&Qb[(size_t)(q0 + fr) * HD + dc * 32 + fg * 8];

    const f16x8_t ones = {(_Float16)1.f, (_Float16)1.f, (_Float16)1.f, (_Float16)1.f,
                          (_Float16)1.f, (_Float16)1.f, (_Float16)1.f, (_Float16)1.f};
    f32x4_t o[4] = {};                 // O[q=fg*4+r][d=df*16+fr]
    f32x4_t lacc = {};                 // l[q=fg*4+r] via ones-MFMA
    float m_run = -1e30f;              // max for q = fr (log2 domain)
    const int mf = mflag[0];

    async_ld16(&sK[0][wv * 512], Kbh + soff);
    async_ld16(&sV[0][wv * 512], Vbh + soff);

    for (int t = 0; t < T_SEQ / 64; ++t) {
        const int cur = t & 1;
        __syncthreads();                       // buf[cur] ready (drains vmcnt)
        if (t + 1 < T_SEQ / 64) {
            async_ld16(&sK[cur ^ 1][wv * 512], Kbh + (t + 1) * 4096 + soff);
            async_ld16(&sV[cur ^ 1][wv * 512], Vbh + (t + 1) * 4096 + soff);
        }

        // ---- S^T = K * Q^T : lane holds S[k=kt*16+fg*4+r][q=fr] ----
        f32x4_t s[4];
        __builtin_amdgcn_s_setprio(1);
#pragma unroll
        for (int kt = 0; kt < 4; ++kt) {
            f16x8_t kf0 = *(const f16x8_t*)&sK[cur][fg * 512       + (kt * 16 + fr) * 8];
            f16x8_t kf1 = *(const f16x8_t*)&sK[cur][(4 + fg) * 512 + (kt * 16 + fr) * 8];
            f32x4_t z = {};
            z     = __builtin_amdgcn_mfma_f32_16x16x32_f16(kf0, qf[0], z, 0, 0, 0);
            s[kt] = __builtin_amdgcn_mfma_f32_16x16x32_f16(kf1, qf[1], z, 0, 0, 0);
        }
        __builtin_amdgcn_s_setprio(0);

        // hoist V fragment reads; LDS latency hides under softmax VALU
        f16x8_t vb[2][4];
#pragma unroll
        for (int kt2 = 0; kt2 < 2; ++kt2)
#pragma unroll
            for (int df = 0; df < 4; ++df)
                vb[kt2][df] = *(const f16x8_t*)&sV[cur][(kt2 * 4 + fg) * 512 + (df * 16 + fr) * 8];

        if (mf) {
            const float* mrow = mask + (size_t)(q0 + fr) * T_SEQ + t * 64;
#pragma unroll
            for (int kt = 0; kt < 4; ++kt)
#pragma unroll
                for (int r = 0; r < 4; ++r)
                    s[kt][r] += mrow[kt * 16 + fg * 4 + r] * LOG2E;
        }

        // ---- online softmax (log2 domain; max3-friendly tree, 2 cross-lane steps) ----
        const float t0 = fmaxf(fmaxf(s[0][0], s[0][1]), s[0][2]);
        const float t1 = fmaxf(fmaxf(s[0][3], s[1][0]), s[1][1]);
        const float t2 = fmaxf(fmaxf(s[1][2], s[1][3]), s[2][0]);
        const float t3 = fmaxf(fmaxf(s[2][1], s[2][2]), s[2][3]);
        const float t4 = fmaxf(fmaxf(s[3][0], s[3][1]), s[3][2]);
        float tmax = fmaxf(fmaxf(fmaxf(t0, t1), fmaxf(t2, t3)), fmaxf(t4, s[3][3]));
        tmax = fmaxf(tmax, __shfl_xor(tmax, 16, 64));
        tmax = fmaxf(tmax, __shfl_xor(tmax, 32, 64));

        if (!__all(tmax <= m_run + 8.0f)) {           // defer-max (T13)
            const float mnew = fmaxf(m_run, tmax);
            const float sc = __builtin_amdgcn_exp2f(m_run - mnew);
            m_run = mnew;
            float scq[4];
#pragma unroll
            for (int r = 0; r < 4; ++r)
                scq[r] = __shfl(sc, fg * 4 + r, 64);
#pragma unroll
            for (int r = 0; r < 4; ++r) {
                lacc[r] *= scq[r];
#pragma unroll
                for (int df = 0; df < 4; ++df)
                    o[df][r] *= scq[r];
            }
        }

#pragma unroll
        for (int kt = 0; kt < 4; ++kt) {
            f16x4_t hp;
#pragma unroll
            for (int r = 0; r < 4; ++r)
                hp[r] = (_Float16)__builtin_amdgcn_exp2f(s[kt][r] - m_run);
            // P[k][q=fr] -> chunk k>>3, elem k&7
            *(f16x4_t*)&Ps[wv][(kt * 2 + (fg >> 1)) * 128 + fr * 8 + (fg & 1) * 4] = hp;
        }

        asm volatile("s_waitcnt lgkmcnt(0)" ::: "memory");  // cross-lane P RAW
        __builtin_amdgcn_sched_barrier(0);

        // ---- O += P * V ; l += P * 1 ----
        __builtin_amdgcn_s_setprio(1);
#pragma unroll
        for (int kt2 = 0; kt2 < 2; ++kt2) {
            f16x8_t pa = *(const f16x8_t*)&Ps[wv][(kt2 * 4 + fg) * 128 + fr * 8];
#pragma unroll
            for (int df = 0; df < 4; ++df)
                o[df] = __builtin_amdgcn_mfma_f32_16x16x32_f16(pa, vb[kt2][df], o[df], 0, 0, 0);
            lacc = __builtin_amdgcn_mfma_f32_16x16x32_f16(pa, ones, lacc, 0, 0, 0);
        }
        __builtin_amdgcn_s_setprio(0);
    }

    // ---- epilogue: normalize, write (B,T,H*D) fp16 ----
#pragma unroll
    for (int r = 0; r < 4; ++r) {
        const float inv = 1.f / lacc[r];
        const size_t row = (size_t)(b * T_SEQ + q0 + fg * 4 + r);
#pragma unroll
        for (int df = 0; df < 4; ++df)
            AO[row * CDIM + h * HD + df * 16 + fr] = (_Float16)(o[df][r] * inv);
    }
}

extern "C" void kernel_launch(void* const* d_in, const int* in_sizes, int n_in,
                              void* d_out, int out_size, void* d_ws, size_t ws_size,
                              hipStream_t stream) {
    const float* x    = (const float*)d_in[0];
    const float* mask = (const float*)d_in[1];
    const float* Wq   = (const float*)d_in[2];
    const float* bq   = (const float*)d_in[3];
    const float* Wk   = (const float*)d_in[4];
    const float* bk   = (const float*)d_in[5];
    const float* Wv   = (const float*)d_in[6];
    const float* bv   = (const float*)d_in[7];
    const float* Wo   = (const float*)d_in[8];
    const float* bo   = (const float*)d_in[9];
    float* out = (float*)d_out;

    char* ws = (char*)d_ws;
    _Float16* xh    = (_Float16*)(ws);                    // 4096x1024  (8MB) -- reused as AO
    _Float16* Wqkvh = (_Float16*)(ws + (8u  << 20));      // 3072x1024  (6MB)
    _Float16* Woh   = (_Float16*)(ws + (14u << 20));      // 1024x1024  (2MB)
    _Float16* Qp    = (_Float16*)(ws + (16u << 20));      // (B,H,T,D)  (8MB)
    _Float16* Kc    = (_Float16*)(ws + (24u << 20));      // chunked    (8MB)
    _Float16* Vc    = (_Float16*)(ws + (32u << 20));      // chunked    (8MB)
    int* mflag      = (int*)(ws + (40u << 20));
    _Float16* AO    = xh;   // alias: x consumed by QKV GEMM before attn writes AO

    hipMemsetAsync(mflag, 0, 4, stream);
    prep_all<<<12288, 256, 0, stream>>>(x, Wq, Wk, Wv, Wo, mask, xh, Wqkvh, Woh, mflag);
    gemm_f16<0><<<768, 256, 0, stream>>>(Wqkvh, xh, bq, bk, bv, Qp, Kc, Vc, nullptr);
    attn_f16<<<512, 512, 0, stream>>>(Qp, Kc, Vc, mask, mflag, AO);
    gemm_f16<1><<<256, 256, 0, stream>>>(Woh, AO, bo, nullptr, nullptr,
                                         nullptr, nullptr, nullptr, out);
}